// Round 9
// baseline (420.539 us; speedup 1.0000x reference)
//
#include <hip/hip_runtime.h>
#include <cstddef>
#include <cstdint>

#define NEGV -1e30f

constexpr int B_    = 32;
constexpr int TXT   = 256;
constexpr int MEL   = 2048;
constexpr int NMEL  = 80;

// 4-step composition groups: group g covers DP steps t = 4g+1 .. 4g+4
constexpr int NGROUPS = 511;    // covers t = 1..2044 (tail steps handled raw)
constexpr int GSTRIDE = 520;    // allocated groups per batch (+ prefetch pad)

#define INV_LN2 1.4426950408889634f
#define LN2     0.6931471805599453f
#define M_DEAD  (-(1 << 30))          // "lane has zero mass" scale marker

typedef float f32x4 __attribute__((ext_vector_type(4)));
typedef unsigned short u16;
typedef unsigned int   u32;

__device__ __forceinline__ float wave_ror1_f(float x) {
    int xi = __float_as_int(x);
    int r  = __builtin_amdgcn_update_dpp(xi, xi, 0x13C /*wave_ror:1*/, 0xF, 0xF, false);
    return __int_as_float(r);
}
__device__ __forceinline__ int wave_ror1_i(int x) {
    return __builtin_amdgcn_update_dpp(x, x, 0x13C, 0xF, 0xF, false);
}
__device__ __forceinline__ float exp2_nat(float x) {
#if __has_builtin(__builtin_amdgcn_exp2f)
    return __builtin_amdgcn_exp2f(x);
#else
    float r; asm("v_exp_f32 %0, %1" : "=v"(r) : "v"(x)); return r;
#endif
}
__device__ __forceinline__ float log2_nat(float x) {
#if __has_builtin(__builtin_amdgcn_logf)
    return __builtin_amdgcn_logf(x);
#else
    float r; asm("v_log_f32 %0, %1" : "=v"(r) : "v"(x)); return r;
#endif
}
__device__ __forceinline__ float ldexp_nat(float x, int n) {
#if __has_builtin(__builtin_amdgcn_ldexpf)
    return __builtin_amdgcn_ldexpf(x, n);
#else
    float r; asm("v_ldexp_f32 %0, %1, %2" : "=v"(r) : "v"(x), "v"(n)); return r;
#endif
}

// fp32 -> bf16 (round-to-nearest-even), result in low 16 bits
__device__ __forceinline__ u32 f2bf(float x) {
    u32 u = __float_as_uint(x);
    u += 0x7FFFu + ((u >> 16) & 1u);
    return u >> 16;
}
// 4 packed bf16 (uint2) -> f32x4
__device__ __forceinline__ f32x4 bf4(uint2 w) {
    f32x4 r;
    r[0] = __uint_as_float(w.x << 16);
    r[1] = __uint_as_float(w.x & 0xFFFF0000u);
    r[2] = __uint_as_float(w.y << 16);
    r[3] = __uint_as_float(w.y & 0xFFFF0000u);
    return r;
}

// ---------------------------------------------------------------------------
// Kernel P: per (b,j): iv[c]=exp(-logvar), m2[c]=2*mu*iv, s = sum(mu^2*iv + logvar)
// ---------------------------------------------------------------------------
__global__ __launch_bounds__(256) void precompute_kernel(
    const float* __restrict__ mu_logvar,
    float* __restrict__ IV, float* __restrict__ M2, float* __restrict__ S)
{
    const int b = blockIdx.x;
    const int j = threadIdx.x;
    const float* row = mu_logvar + (size_t)(b * TXT + j) * (2 * NMEL);
    float s = 0.f;
    for (int c = 0; c < NMEL; ++c) {
        float mu = row[c];
        float lv = row[NMEL + c];
        float iv = expf(-lv);
        IV[(b * NMEL + c) * TXT + j] = iv;
        M2[(b * NMEL + c) * TXT + j] = 2.0f * mu * iv;
        s += mu * mu * iv + lv;
    }
    S[b * TXT + j] = s;
}

// ---------------------------------------------------------------------------
// Kernel 1: log_prob. out1 = exact ln values (fp32, checked output).
// lpT[b][t][j] = p = exp(lp) stored as BF16 (R8: internal intermediates go
// bf16 — loss error is /ml at the end; saves 32MB write + 32MB read).
// ---------------------------------------------------------------------------
__global__ __launch_bounds__(256) void logprob_kernel(
    const float* __restrict__ mel,
    const float* __restrict__ IV, const float* __restrict__ M2,
    const float* __restrict__ S,
    float* __restrict__ out1,
    u16* __restrict__ lpT,
    int write_lpT)
{
    const int tt0 = blockIdx.x * 128;
    const int j0  = blockIdx.y * 64;
    const int b   = blockIdx.z;
    const int tx  = threadIdx.x & 15;
    const int ty  = threadIdx.x >> 4;

    __shared__ union SM {
        struct { float IV[NMEL][64]; float M2[NMEL][64]; } stage;
        float V[64][132];
    } sm;

    for (int idx = threadIdx.x; idx < NMEL * 64; idx += 256) {
        int c  = idx >> 6;
        int jj = idx & 63;
        sm.stage.IV[c][jj] = IV[(b * NMEL + c) * TXT + j0 + jj];
        sm.stage.M2[c][jj] = M2[(b * NMEL + c) * TXT + j0 + jj];
    }
    __syncthreads();

    float acc[4][8];
#pragma unroll
    for (int a = 0; a < 4; ++a)
#pragma unroll
        for (int d = 0; d < 8; ++d) acc[a][d] = 0.f;

    const float* melb = mel + (size_t)b * NMEL * MEL + tt0 + tx;

#pragma unroll 2
    for (int c = 0; c < NMEL; ++c) {
        float x[8];
#pragma unroll
        for (int d = 0; d < 8; ++d) x[d] = melb[(size_t)c * MEL + 16 * d];
        float4 iv = *(const float4*)&sm.stage.IV[c][ty * 4];
        float4 m2 = *(const float4*)&sm.stage.M2[c][ty * 4];
        float ivr[4] = {iv.x, iv.y, iv.z, iv.w};
        float m2r[4] = {m2.x, m2.y, m2.z, m2.w};
#pragma unroll
        for (int a = 0; a < 4; ++a) {
#pragma unroll
            for (int d = 0; d < 8; ++d) {
                float tmp = fmaf(ivr[a], x[d], -m2r[a]);
                acc[a][d] = fmaf(tmp, x[d], acc[a][d]);
            }
        }
    }

    const float c0 = -0.5f / (float)NMEL;
    float4 sj = *(const float4*)&S[b * TXT + j0 + ty * 4];
    float sjr[4] = {sj.x, sj.y, sj.z, sj.w};

    __syncthreads();
#pragma unroll
    for (int a = 0; a < 4; ++a) {
        const int jl = ty * 4 + a;
#pragma unroll
        for (int d = 0; d < 8; ++d) {
            sm.V[jl][tx + 16 * d] = c0 * (acc[a][d] + sjr[a]);
        }
    }
    __syncthreads();

    const int tid = threadIdx.x;

    {
        const int t4 = (tid & 31) * 4;
        const int jb = tid >> 5;
#pragma unroll
        for (int k = 0; k < 8; ++k) {
            const int jl = jb + 8 * k;
            float4 v = *(const float4*)&sm.V[jl][t4];
            *(float4*)&out1[(size_t)(b * TXT + j0 + jl) * MEL + tt0 + t4] = v;
        }
    }

    if (write_lpT) {
        const int j4 = (tid & 15) * 4;
        const int tb = tid >> 4;
#pragma unroll
        for (int k = 0; k < 8; ++k) {
            const int tl = tb + 16 * k;
            float pa = exp2_nat(sm.V[j4 + 0][tl] * INV_LN2);
            float pb = exp2_nat(sm.V[j4 + 1][tl] * INV_LN2);
            float pc = exp2_nat(sm.V[j4 + 2][tl] * INV_LN2);
            float pd = exp2_nat(sm.V[j4 + 3][tl] * INV_LN2);
            uint2 w;
            w.x = f2bf(pa) | (f2bf(pb) << 16);
            w.y = f2bf(pc) | (f2bf(pd) << 16);
            *(uint2*)&lpT[((size_t)b * MEL + tt0 + tl) * TXT + j0 + j4] = w;
        }
    }
}

// ---------------------------------------------------------------------------
// Coeff kernel: 4-step composed transition coefficients (band DP, verified
// R7: p==1 -> 1,4,6,4,1). R8: reads bf16 lpT (decoded to f32 LDS tile so the
// band math is byte-identical to R7), writes bf16 coef. Traffic 149->75MB.
// ---------------------------------------------------------------------------
__global__ __launch_bounds__(256) void coeff_kernel(
    const u16* __restrict__ lpT, u16* __restrict__ coef)
{
    const int c = blockIdx.x;          // chunk: groups 8c..8c+7
    const int b = blockIdx.y;
    const int j = threadIdx.x;

    __shared__ float sp[32][256];      // p rows 32c+1 .. 32c+32, decoded f32
    const int r0 = 32 * c + 1;
    const u32* src32 = (const u32*)(lpT + (size_t)b * MEL * TXT);
    for (int idx = threadIdx.x; idx < 32 * 128; idx += 256) {
        int row = idx >> 7;
        int col = idx & 127;
        u32 w = src32[(size_t)(r0 + row) * 128 + col];   // row <= 2048 < pad
        sp[row][2 * col]     = __uint_as_float(w << 16);
        sp[row][2 * col + 1] = __uint_as_float(w & 0xFFFF0000u);
    }
    __syncthreads();

    const int jm1 = (j >= 1) ? j - 1 : 0;
    const int jm2 = (j >= 2) ? j - 2 : 0;
    const int jm3 = (j >= 3) ? j - 3 : 0;

#pragma unroll 2
    for (int gi = 0; gi < 8; ++gi) {
        int g = 8 * c + gi;
        if (g >= NGROUPS) break;
        const float* P1 = sp[4 * gi + 0];
        const float* P2 = sp[4 * gi + 1];
        const float* P3 = sp[4 * gi + 2];
        const float* P4 = sp[4 * gi + 3];
        float p1_0 = P1[j], p1_1 = P1[jm1], p1_2 = P1[jm2], p1_3 = P1[jm3];
        float p2_0 = P2[j], p2_1 = P2[jm1], p2_2 = P2[jm2];
        float p3_0 = P3[j], p3_1 = P3[jm1];
        float p4_0 = P4[j];
        float A0 = p2_0 * p1_0, A1 = p2_0 * (p1_0 + p1_1), A2 = p2_0 * p1_1;
        float B0 = p2_1 * p1_1, B1 = p2_1 * (p1_1 + p1_2), B2 = p2_1 * p1_2;
        float D0 = p2_2 * p1_2, D1 = p2_2 * (p1_2 + p1_3), D2 = p2_2 * p1_3;
        float E0 = p3_0 * A0, E1 = p3_0 * (A1 + B0), E2 = p3_0 * (A2 + B1), E3 = p3_0 * B2;
        float F0 = p3_1 * B0, F1 = p3_1 * (B1 + D0), F2 = p3_1 * (B2 + D1), F3 = p3_1 * D2;
        u16* dst = coef + (((size_t)b * GSTRIDE + g) * 5) * 256 + j;
        dst[0]    = (u16)f2bf(p4_0 * E0);
        dst[256]  = (u16)f2bf(p4_0 * (E1 + F0));
        dst[512]  = (u16)f2bf(p4_0 * (E2 + F1));
        dst[768]  = (u16)f2bf(p4_0 * (E3 + F2));
        dst[1024] = (u16)f2bf(p4_0 * F3);
    }
}

// ---------------------------------------------------------------------------
// DP kernel v9 (superstep, bf16 coef): 4 DP steps per iteration.
// Ring: 8 slots x 3072B LDS. Per superstep 5 coef rows = 2560B, DMA'd as
// 3 x (64 lanes x 16B) = 3072B (512B over-read lands in coef's GSTRIDE pad).
// DMA depth 7 supersteps = 21 loads; counted vmcnt(21). Decode on read:
// 1 shift/AND per coef. Scale/band math identical to R7 (verified).
// ---------------------------------------------------------------------------
__global__ __launch_bounds__(64, 1) void dp_super_kernel(
    const u16* __restrict__ lpT,
    const u16* __restrict__ coef,
    const int* __restrict__ tlen, const int* __restrict__ mlen,
    float* __restrict__ alpha)
{
    const int b = blockIdx.x;
    const int l = threadIdx.x;          // 0..63

    const int tl   = tlen[b];
    const int ml   = mlen[b];
    const int tmax = ml - 1;
    const int jt   = tl - 1;
    const float out_scale = LN2 / (float)ml;

    const u16* sbase = lpT  + (size_t)b * MEL * TXT;
    const u16* cb    = coef + (size_t)b * GSTRIDE * 5 * 256;
    const bool z = (l == 0);

    __shared__ __align__(16) u16 ring[8][1536];   // 8 slots x 3072B

    // t = 0 init
    f32x4 ld0 = bf4(*(const uint2*)(sbase + l * 4));
    int   ex0 = (int)(__float_as_uint(ld0[0]) >> 23) - 126;
    float q0n = ldexp_nat(ld0[0], -ex0);
    float q0 = z ? q0n : 0.f;
    float q1 = 0.f, q2 = 0.f, q3 = 0.f;
    int   M  = z ? ex0 : M_DEAD;

    if (tmax <= 0) {
        if (l == (jt >> 2)) {
            float vv = (jt == 0) ? log2_nat(ld0[0]) : NEGV;
            alpha[b] = vv * out_scale;
        }
        return;
    }

    __builtin_amdgcn_sched_barrier(0);

    const int nss  = tmax >> 2;
    const int tail = tmax & 3;

#define ISSUE_SS(S)                                                           \
    {                                                                         \
        const u16* s_ = cb + (size_t)(S) * 1280;                              \
        u16* d_ = &ring[(S) & 7][0];                                          \
        __builtin_amdgcn_global_load_lds(                                     \
            (const __attribute__((address_space(1))) void*)(s_ + l * 8),      \
            (__attribute__((address_space(3))) void*)d_, 16, 0, 0);           \
        __builtin_amdgcn_global_load_lds(                                     \
            (const __attribute__((address_space(1))) void*)(s_ + 512 + l * 8),\
            (__attribute__((address_space(3))) void*)(d_ + 512), 16, 0, 0);   \
        __builtin_amdgcn_global_load_lds(                                     \
            (const __attribute__((address_space(1))) void*)(s_ + 1024 + l * 8),\
            (__attribute__((address_space(3))) void*)(d_ + 1024), 16, 0, 0);  \
    }

    // prologue: supersteps 0..6 in flight (21 loads)
#pragma unroll
    for (int s = 0; s < 7; ++s) ISSUE_SS(s);

    for (int s = 0; s < nss; ++s) {
        ISSUE_SS(s + 7);                // max S = nss+6 <= 517 < GSTRIDE pad
        // 24 outstanding; wait for oldest 3 (superstep s) to land
        asm volatile("s_waitcnt vmcnt(21)" ::: "memory");
        __builtin_amdgcn_sched_barrier(0);
        const u16* rs = &ring[s & 7][0];
        f32x4 C0 = bf4(*(const uint2*)(rs +    0 + l * 4));
        f32x4 C1 = bf4(*(const uint2*)(rs +  256 + l * 4));
        f32x4 C2 = bf4(*(const uint2*)(rs +  512 + l * 4));
        f32x4 C3 = bf4(*(const uint2*)(rs +  768 + l * 4));
        f32x4 C4 = bf4(*(const uint2*)(rs + 1024 + l * 4));

        // boundary exchange
        float bq0 = wave_ror1_f(q0), bq1 = wave_ror1_f(q1);
        float bq2 = wave_ror1_f(q2), bq3 = wave_ror1_f(q3);
        int   bM  = wave_ror1_i(M);

        int dq   = z ? (-(1 << 28)) : (bM - M);
        int sin_ = (dq < 0) ? dq  : 0;
        int sown = (dq > 0) ? -dq : 0;
        int mup  = (dq > 0) ? dq  : 0;

        float a0 = ldexp_nat(q0, sown), a1 = ldexp_nat(q1, sown);
        float a2 = ldexp_nat(q2, sown), a3 = ldexp_nat(q3, sown);
        float b0 = ldexp_nat(bq0, sin_), b1 = ldexp_nat(bq1, sin_);
        float b2 = ldexp_nat(bq2, sin_), b3 = ldexp_nat(bq3, sin_);

        float y0 = fmaf(C1[0], b3, fmaf(C2[0], b2, fmaf(C3[0], b1, fmaf(C4[0], b0, C0[0] * a0))));
        float y1 = fmaf(C2[1], b3, fmaf(C3[1], b2, fmaf(C4[1], b1, fmaf(C1[1], a0, C0[1] * a1))));
        float y2 = fmaf(C3[2], b3, fmaf(C4[2], b2, fmaf(C1[2], a1, fmaf(C2[2], a0, C0[2] * a2))));
        float y3 = fmaf(C4[3], b3, fmaf(C1[3], a2, fmaf(C2[3], a1, fmaf(C3[3], a0, C0[3] * a3))));

        float mloc = fmaxf(fmaxf(y0, y1), fmaxf(y2, y3));
        int ex  = (int)(__float_as_uint(mloc) >> 23) - 126;
        int nex = -ex;
        q0 = ldexp_nat(y0, nex); q1 = ldexp_nat(y1, nex);
        q2 = ldexp_nat(y2, nex); q3 = ldexp_nat(y3, nex);
        int Mn = M + mup + ex;
        M = (mloc > 0.f) ? Mn : M_DEAD;
    }

    asm volatile("s_waitcnt vmcnt(0)" ::: "memory");
    __builtin_amdgcn_sched_barrier(0);

    // tail: 0..3 raw single steps on bf16 p rows (rows <= tmax <= 2047)
    {
        const int t0 = 4 * nss + 1;
        f32x4 pr0 = bf4(*(const uint2*)(sbase + (size_t)(t0 + 0) * TXT + l * 4));
        f32x4 pr1 = bf4(*(const uint2*)(sbase + (size_t)(t0 + 1) * TXT + l * 4));
        f32x4 pr2 = bf4(*(const uint2*)(sbase + (size_t)(t0 + 2) * TXT + l * 4));

#define STEP1(P)                                                   \
    {                                                              \
        float qb = wave_ror1_f(q3);                                \
        int   Mb = wave_ror1_i(M);                                 \
        int dq   = z ? (-(1 << 28)) : (Mb - M);                    \
        int si   = (dq < 0) ? dq  : 0;                             \
        int so   = (dq > 0) ? -dq : 0;                             \
        int mu   = (dq > 0) ? dq  : 0;                             \
        float a0 = ldexp_nat(q0, so), a1 = ldexp_nat(q1, so);      \
        float a2 = ldexp_nat(q2, so), a3 = ldexp_nat(q3, so);      \
        float bb = ldexp_nat(qb, si);                              \
        q0 = (a0 + bb) * (P)[0];                                   \
        q1 = (a1 + a0) * (P)[1];                                   \
        q2 = (a2 + a1) * (P)[2];                                   \
        q3 = (a3 + a2) * (P)[3];                                   \
        M += mu;                                                   \
    }
        if (tail >= 1) STEP1(pr0);
        if (tail >= 2) STEP1(pr1);
        if (tail >= 3) STEP1(pr2);
#undef STEP1
    }
#undef ISSUE_SS

    const int lf = jt >> 2;
    const int ef = jt & 3;
    float v = (ef == 0) ? q0 : (ef == 1) ? q1 : (ef == 2) ? q2 : q3;
    if (l == lf) alpha[b] = (log2_nat(v) + (float)M) * out_scale;
}

// ---------------------------------------------------------------------------
// DP fallback (un-transposed, ln-domain reads from out1) — safety net.
// ---------------------------------------------------------------------------
__global__ __launch_bounds__(256) void dp_kernel_fallback(
    const float* __restrict__ lp,
    const int* __restrict__ tlen, const int* __restrict__ mlen,
    float* __restrict__ alpha)
{
    const int b    = blockIdx.x;
    const int j    = threadIdx.x;
    const int lane = j & 63;
    const int w    = j >> 6;

    const int tl   = tlen[b];
    const int ml   = mlen[b];
    const int tmax = ml - 1;
    const int jt   = tl - 1;
    const float inv_ml = 1.0f / (float)ml;

    __shared__ float bnd[2][4];
    if (threadIdx.x < 8) bnd[threadIdx.x >> 2][threadIdx.x & 3] = NEGV;
    __syncthreads();

    float cur = (j == 0) ? lp[(size_t)(b * TXT) * MEL] : NEGV;
    if (tmax == 0) {
        if (j == jt) alpha[b] = cur * inv_ml;
        return;
    }
    int p = 0;
    for (int t = 1; t <= tmax; ++t) {
        float lpc = lp[((size_t)(b * TXT + j)) * MEL + t];
        float sh = __shfl_up(cur, 1);
        if (lane == 0) sh = (w > 0) ? bnd[p][w - 1] : NEGV;
        float mx = fmaxf(cur, sh);
        float dd = fminf(cur, sh) - mx;
        float nv = mx + __logf(1.0f + __expf(dd)) + lpc;
        if (lane == 63) bnd[p ^ 1][w] = nv;
        if (t == tmax && j == jt) alpha[b] = nv * inv_ml;
        cur = nv;
        __syncthreads();
        p ^= 1;
    }
}

// ---------------------------------------------------------------------------
// Reduce: loss = -mean_b(alpha[b])
// ---------------------------------------------------------------------------
__global__ void reduce_kernel(const float* __restrict__ alpha, float* __restrict__ out)
{
    const int tid = threadIdx.x;
    float v = (tid < B_) ? alpha[tid] : 0.f;
#pragma unroll
    for (int m = 16; m >= 1; m >>= 1) v += __shfl_xor(v, m);
    if (tid == 0) out[0] = -v / (float)B_;
}

// ---------------------------------------------------------------------------
extern "C" void kernel_launch(void* const* d_in, const int* in_sizes, int n_in,
                              void* d_out, int out_size, void* d_ws, size_t ws_size,
                              hipStream_t stream)
{
    const float* mu_logvar = (const float*)d_in[0];
    const float* melspec   = (const float*)d_in[1];
    const int*   tlen      = (const int*)d_in[2];
    const int*   mlen      = (const int*)d_in[3];
    float* out = (float*)d_out;
    float* ws  = (float*)d_ws;

    // ws layout (in float units)
    const size_t IV_OFF    = 0;                        // 655360
    const size_t M2_OFF    = 655360;                   // 655360
    const size_t S_OFF     = 1310720;                  // 8192
    const size_t ALPHA_OFF = 1318912;                  // 32
    const size_t LPT_OFF   = 1318944;                  // bf16: B*MEL*TXT u16
    const size_t LPT_FLOATS = (size_t)B_ * MEL * TXT / 2;      // 8,388,608
    const size_t LPT_PAD_F  = 2048;                    // 16 rows x 256 u16
    const size_t COEF_OFF  = LPT_OFF + LPT_FLOATS + LPT_PAD_F; // 9,709,600
    const size_t COEF_FLOATS = (size_t)B_ * GSTRIDE * 5 * 256 / 2; // 10,649,600

    float* IV    = ws + IV_OFF;
    float* M2    = ws + M2_OFF;
    float* S     = ws + S_OFF;
    float* alpha = ws + ALPHA_OFF;
    u16*   lpT   = (u16*)(ws + LPT_OFF);
    u16*   coef  = (u16*)(ws + COEF_OFF);

    const bool use_coef = ws_size >= (COEF_OFF + COEF_FLOATS) * sizeof(float);

    precompute_kernel<<<dim3(B_), dim3(256), 0, stream>>>(mu_logvar, IV, M2, S);

    logprob_kernel<<<dim3(MEL / 128, TXT / 64, B_), dim3(256), 0, stream>>>(
        melspec, IV, M2, S, out + 1, lpT, use_coef ? 1 : 0);

    if (use_coef) {
        coeff_kernel<<<dim3(64, B_), dim3(256), 0, stream>>>(lpT, coef);
        dp_super_kernel<<<dim3(B_), dim3(64), 0, stream>>>(lpT, coef, tlen, mlen, alpha);
    } else {
        dp_kernel_fallback<<<dim3(B_), dim3(256), 0, stream>>>(out + 1, tlen, mlen, alpha);
    }

    reduce_kernel<<<dim3(1), dim3(64), 0, stream>>>(alpha, out);
}

// Round 10
// 301.128 us; speedup vs baseline: 1.3965x; 1.3965x over previous
//
#include <hip/hip_runtime.h>
#include <cstddef>
#include <cstdint>

#define NEGV -1e30f

constexpr int B_    = 32;
constexpr int TXT   = 256;
constexpr int MEL   = 2048;
constexpr int NMEL  = 80;

// 4-step composition groups: group g covers DP steps t = 4g+1 .. 4g+4
constexpr int NGROUPS = 511;    // covers t = 1..2044 (tail steps handled raw)
constexpr int GSTRIDE = 520;    // allocated groups per batch (+ prefetch pad)

#define INV_LN2 1.4426950408889634f
#define LN2     0.6931471805599453f
#define M_DEAD  (-(1 << 30))          // "lane has zero mass" scale marker

typedef float f32x4 __attribute__((ext_vector_type(4)));
typedef unsigned short u16;
typedef unsigned int   u32;

__device__ __forceinline__ float wave_ror1_f(float x) {
    int xi = __float_as_int(x);
    int r  = __builtin_amdgcn_update_dpp(xi, xi, 0x13C /*wave_ror:1*/, 0xF, 0xF, false);
    return __int_as_float(r);
}
__device__ __forceinline__ int wave_ror1_i(int x) {
    return __builtin_amdgcn_update_dpp(x, x, 0x13C, 0xF, 0xF, false);
}
__device__ __forceinline__ float exp2_nat(float x) {
#if __has_builtin(__builtin_amdgcn_exp2f)
    return __builtin_amdgcn_exp2f(x);
#else
    float r; asm("v_exp_f32 %0, %1" : "=v"(r) : "v"(x)); return r;
#endif
}
__device__ __forceinline__ float log2_nat(float x) {
#if __has_builtin(__builtin_amdgcn_logf)
    return __builtin_amdgcn_logf(x);
#else
    float r; asm("v_log_f32 %0, %1" : "=v"(r) : "v"(x)); return r;
#endif
}
__device__ __forceinline__ float ldexp_nat(float x, int n) {
#if __has_builtin(__builtin_amdgcn_ldexpf)
    return __builtin_amdgcn_ldexpf(x, n);
#else
    float r; asm("v_ldexp_f32 %0, %1, %2" : "=v"(r) : "v"(x), "v"(n)); return r;
#endif
}

// fp32 -> bf16 (round-to-nearest-even), result in low 16 bits
__device__ __forceinline__ u32 f2bf(float x) {
    u32 u = __float_as_uint(x);
    u += 0x7FFFu + ((u >> 16) & 1u);
    return u >> 16;
}
// 4 packed bf16 (uint2) -> f32x4
__device__ __forceinline__ f32x4 bf4(uint2 w) {
    f32x4 r;
    r[0] = __uint_as_float(w.x << 16);
    r[1] = __uint_as_float(w.x & 0xFFFF0000u);
    r[2] = __uint_as_float(w.y << 16);
    r[3] = __uint_as_float(w.y & 0xFFFF0000u);
    return r;
}
// generic LDS pointer -> 32-bit LDS byte offset (for asm ds_read)
__device__ __forceinline__ unsigned lds_off(const void* p) {
    return (unsigned)(unsigned long long)
        (const __attribute__((address_space(3))) char*)p;
}

// ---------------------------------------------------------------------------
// Kernel P: per (b,j): iv[c]=exp(-logvar), m2[c]=2*mu*iv, s = sum(mu^2*iv + logvar)
// ---------------------------------------------------------------------------
__global__ __launch_bounds__(256) void precompute_kernel(
    const float* __restrict__ mu_logvar,
    float* __restrict__ IV, float* __restrict__ M2, float* __restrict__ S)
{
    const int b = blockIdx.x;
    const int j = threadIdx.x;
    const float* row = mu_logvar + (size_t)(b * TXT + j) * (2 * NMEL);
    float s = 0.f;
    for (int c = 0; c < NMEL; ++c) {
        float mu = row[c];
        float lv = row[NMEL + c];
        float iv = expf(-lv);
        IV[(b * NMEL + c) * TXT + j] = iv;
        M2[(b * NMEL + c) * TXT + j] = 2.0f * mu * iv;
        s += mu * mu * iv + lv;
    }
    S[b * TXT + j] = s;
}

// ---------------------------------------------------------------------------
// Kernel 1: log_prob. out1 = exact ln values (fp32, checked output).
// lpT[b][t][j] = p = exp(lp) stored as BF16.
// ---------------------------------------------------------------------------
__global__ __launch_bounds__(256) void logprob_kernel(
    const float* __restrict__ mel,
    const float* __restrict__ IV, const float* __restrict__ M2,
    const float* __restrict__ S,
    float* __restrict__ out1,
    u16* __restrict__ lpT,
    int write_lpT)
{
    const int tt0 = blockIdx.x * 128;
    const int j0  = blockIdx.y * 64;
    const int b   = blockIdx.z;
    const int tx  = threadIdx.x & 15;
    const int ty  = threadIdx.x >> 4;

    __shared__ union SM {
        struct { float IV[NMEL][64]; float M2[NMEL][64]; } stage;
        float V[64][132];
    } sm;

    for (int idx = threadIdx.x; idx < NMEL * 64; idx += 256) {
        int c  = idx >> 6;
        int jj = idx & 63;
        sm.stage.IV[c][jj] = IV[(b * NMEL + c) * TXT + j0 + jj];
        sm.stage.M2[c][jj] = M2[(b * NMEL + c) * TXT + j0 + jj];
    }
    __syncthreads();

    float acc[4][8];
#pragma unroll
    for (int a = 0; a < 4; ++a)
#pragma unroll
        for (int d = 0; d < 8; ++d) acc[a][d] = 0.f;

    const float* melb = mel + (size_t)b * NMEL * MEL + tt0 + tx;

#pragma unroll 2
    for (int c = 0; c < NMEL; ++c) {
        float x[8];
#pragma unroll
        for (int d = 0; d < 8; ++d) x[d] = melb[(size_t)c * MEL + 16 * d];
        float4 iv = *(const float4*)&sm.stage.IV[c][ty * 4];
        float4 m2 = *(const float4*)&sm.stage.M2[c][ty * 4];
        float ivr[4] = {iv.x, iv.y, iv.z, iv.w};
        float m2r[4] = {m2.x, m2.y, m2.z, m2.w};
#pragma unroll
        for (int a = 0; a < 4; ++a) {
#pragma unroll
            for (int d = 0; d < 8; ++d) {
                float tmp = fmaf(ivr[a], x[d], -m2r[a]);
                acc[a][d] = fmaf(tmp, x[d], acc[a][d]);
            }
        }
    }

    const float c0 = -0.5f / (float)NMEL;
    float4 sj = *(const float4*)&S[b * TXT + j0 + ty * 4];
    float sjr[4] = {sj.x, sj.y, sj.z, sj.w};

    __syncthreads();
#pragma unroll
    for (int a = 0; a < 4; ++a) {
        const int jl = ty * 4 + a;
#pragma unroll
        for (int d = 0; d < 8; ++d) {
            sm.V[jl][tx + 16 * d] = c0 * (acc[a][d] + sjr[a]);
        }
    }
    __syncthreads();

    const int tid = threadIdx.x;

    {
        const int t4 = (tid & 31) * 4;
        const int jb = tid >> 5;
#pragma unroll
        for (int k = 0; k < 8; ++k) {
            const int jl = jb + 8 * k;
            float4 v = *(const float4*)&sm.V[jl][t4];
            *(float4*)&out1[(size_t)(b * TXT + j0 + jl) * MEL + tt0 + t4] = v;
        }
    }

    if (write_lpT) {
        const int j4 = (tid & 15) * 4;
        const int tb = tid >> 4;
#pragma unroll
        for (int k = 0; k < 8; ++k) {
            const int tl = tb + 16 * k;
            float pa = exp2_nat(sm.V[j4 + 0][tl] * INV_LN2);
            float pb = exp2_nat(sm.V[j4 + 1][tl] * INV_LN2);
            float pc = exp2_nat(sm.V[j4 + 2][tl] * INV_LN2);
            float pd = exp2_nat(sm.V[j4 + 3][tl] * INV_LN2);
            uint2 w;
            w.x = f2bf(pa) | (f2bf(pb) << 16);
            w.y = f2bf(pc) | (f2bf(pd) << 16);
            *(uint2*)&lpT[((size_t)b * MEL + tt0 + tl) * TXT + j0 + j4] = w;
        }
    }
}

// ---------------------------------------------------------------------------
// Coeff kernel: 4-step composed transition coefficients (band DP, verified
// R7: p==1 -> 1,4,6,4,1). Reads bf16 lpT, writes bf16 coef.
// ---------------------------------------------------------------------------
__global__ __launch_bounds__(256) void coeff_kernel(
    const u16* __restrict__ lpT, u16* __restrict__ coef)
{
    const int c = blockIdx.x;          // chunk: groups 8c..8c+7
    const int b = blockIdx.y;
    const int j = threadIdx.x;

    __shared__ float sp[32][256];      // p rows 32c+1 .. 32c+32, decoded f32
    const int r0 = 32 * c + 1;
    const u32* src32 = (const u32*)(lpT + (size_t)b * MEL * TXT);
    for (int idx = threadIdx.x; idx < 32 * 128; idx += 256) {
        int row = idx >> 7;
        int col = idx & 127;
        u32 w = src32[(size_t)(r0 + row) * 128 + col];   // row <= 2048 < pad
        sp[row][2 * col]     = __uint_as_float(w << 16);
        sp[row][2 * col + 1] = __uint_as_float(w & 0xFFFF0000u);
    }
    __syncthreads();

    const int jm1 = (j >= 1) ? j - 1 : 0;
    const int jm2 = (j >= 2) ? j - 2 : 0;
    const int jm3 = (j >= 3) ? j - 3 : 0;

#pragma unroll 2
    for (int gi = 0; gi < 8; ++gi) {
        int g = 8 * c + gi;
        if (g >= NGROUPS) break;
        const float* P1 = sp[4 * gi + 0];
        const float* P2 = sp[4 * gi + 1];
        const float* P3 = sp[4 * gi + 2];
        const float* P4 = sp[4 * gi + 3];
        float p1_0 = P1[j], p1_1 = P1[jm1], p1_2 = P1[jm2], p1_3 = P1[jm3];
        float p2_0 = P2[j], p2_1 = P2[jm1], p2_2 = P2[jm2];
        float p3_0 = P3[j], p3_1 = P3[jm1];
        float p4_0 = P4[j];
        float A0 = p2_0 * p1_0, A1 = p2_0 * (p1_0 + p1_1), A2 = p2_0 * p1_1;
        float B0 = p2_1 * p1_1, B1 = p2_1 * (p1_1 + p1_2), B2 = p2_1 * p1_2;
        float D0 = p2_2 * p1_2, D1 = p2_2 * (p1_2 + p1_3), D2 = p2_2 * p1_3;
        float E0 = p3_0 * A0, E1 = p3_0 * (A1 + B0), E2 = p3_0 * (A2 + B1), E3 = p3_0 * B2;
        float F0 = p3_1 * B0, F1 = p3_1 * (B1 + D0), F2 = p3_1 * (B2 + D1), F3 = p3_1 * D2;
        u16* dst = coef + (((size_t)b * GSTRIDE + g) * 5) * 256 + j;
        dst[0]    = (u16)f2bf(p4_0 * E0);
        dst[256]  = (u16)f2bf(p4_0 * (E1 + F0));
        dst[512]  = (u16)f2bf(p4_0 * (E2 + F1));
        dst[768]  = (u16)f2bf(p4_0 * (E3 + F2));
        dst[1024] = (u16)f2bf(p4_0 * F3);
    }
}

// ---------------------------------------------------------------------------
// DP kernel v10: R9 counters showed 1056 cy/superstep with only ~23% issue —
// ~800 cy of exposed memory latency despite the 7-deep DMA ring. Theory: the
// compiler's waitcnt pass cannot disambiguate the runtime-indexed ring-slot
// ds_reads from the in-flight LDS-DMAs (global_load_lds) and inserts its own
// conservative vmcnt drain before them, overriding our counted vmcnt(21).
// R10 change: ring reads via inline-asm ds_read_b64 (opaque to the waitcnt
// pass; 32-bit LDS offset + offset: immediates) + explicit lgkmcnt(0) +
// sched_barrier(0) (rule #18). HW correctness carried by vmcnt(21): slot s's
// DMA retired => its LDS bytes are written. All else identical to R9.
// ---------------------------------------------------------------------------
__global__ __launch_bounds__(64, 1) void dp_super_kernel(
    const u16* __restrict__ lpT,
    const u16* __restrict__ coef,
    const int* __restrict__ tlen, const int* __restrict__ mlen,
    float* __restrict__ alpha)
{
    const int b = blockIdx.x;
    const int l = threadIdx.x;          // 0..63

    const int tl   = tlen[b];
    const int ml   = mlen[b];
    const int tmax = ml - 1;
    const int jt   = tl - 1;
    const float out_scale = LN2 / (float)ml;

    const u16* sbase = lpT  + (size_t)b * MEL * TXT;
    const u16* cb    = coef + (size_t)b * GSTRIDE * 5 * 256;
    const bool z = (l == 0);

    __shared__ __align__(16) u16 ring[8][1536];   // 8 slots x 3072B (only LDS object)

    // t = 0 init
    f32x4 ld0 = bf4(*(const uint2*)(sbase + l * 4));
    int   ex0 = (int)(__float_as_uint(ld0[0]) >> 23) - 126;
    float q0n = ldexp_nat(ld0[0], -ex0);
    float q0 = z ? q0n : 0.f;
    float q1 = 0.f, q2 = 0.f, q3 = 0.f;
    int   M  = z ? ex0 : M_DEAD;

    if (tmax <= 0) {
        if (l == (jt >> 2)) {
            float vv = (jt == 0) ? log2_nat(ld0[0]) : NEGV;
            alpha[b] = vv * out_scale;
        }
        return;
    }

    __builtin_amdgcn_sched_barrier(0);

    const int nss  = tmax >> 2;
    const int tail = tmax & 3;

#define ISSUE_SS(S)                                                           \
    {                                                                         \
        const u16* s_ = cb + (size_t)(S) * 1280;                              \
        u16* d_ = &ring[(S) & 7][0];                                          \
        __builtin_amdgcn_global_load_lds(                                     \
            (const __attribute__((address_space(1))) void*)(s_ + l * 8),      \
            (__attribute__((address_space(3))) void*)d_, 16, 0, 0);           \
        __builtin_amdgcn_global_load_lds(                                     \
            (const __attribute__((address_space(1))) void*)(s_ + 512 + l * 8),\
            (__attribute__((address_space(3))) void*)(d_ + 512), 16, 0, 0);   \
        __builtin_amdgcn_global_load_lds(                                     \
            (const __attribute__((address_space(1))) void*)(s_ + 1024 + l * 8),\
            (__attribute__((address_space(3))) void*)(d_ + 1024), 16, 0, 0);  \
    }

    // prologue: supersteps 0..6 in flight (21 loads)
#pragma unroll
    for (int s = 0; s < 7; ++s) ISSUE_SS(s);

    for (int s = 0; s < nss; ++s) {
        ISSUE_SS(s + 7);                // max S = nss+6 <= 517 < GSTRIDE pad
        // 24 outstanding; wait for oldest 3 (superstep s) to land
        asm volatile("s_waitcnt vmcnt(21)" ::: "memory");
        __builtin_amdgcn_sched_barrier(0);

        // asm ds_reads: opaque to compiler waitcnt insertion (the R10 fix)
        const unsigned base = lds_off(&ring[s & 7][0]) + (unsigned)(l * 8);
        uint2 w0, w1, w2, w3, w4;
        asm volatile("ds_read_b64 %0, %1 offset:0"    : "=v"(w0) : "v"(base));
        asm volatile("ds_read_b64 %0, %1 offset:512"  : "=v"(w1) : "v"(base));
        asm volatile("ds_read_b64 %0, %1 offset:1024" : "=v"(w2) : "v"(base));
        asm volatile("ds_read_b64 %0, %1 offset:1536" : "=v"(w3) : "v"(base));
        asm volatile("ds_read_b64 %0, %1 offset:2048" : "=v"(w4) : "v"(base));
        asm volatile("s_waitcnt lgkmcnt(0)");
        __builtin_amdgcn_sched_barrier(0);   // rule #18: pin VALU below the wait

        f32x4 C0 = bf4(w0);
        f32x4 C1 = bf4(w1);
        f32x4 C2 = bf4(w2);
        f32x4 C3 = bf4(w3);
        f32x4 C4 = bf4(w4);

        // boundary exchange
        float bq0 = wave_ror1_f(q0), bq1 = wave_ror1_f(q1);
        float bq2 = wave_ror1_f(q2), bq3 = wave_ror1_f(q3);
        int   bM  = wave_ror1_i(M);

        int dq   = z ? (-(1 << 28)) : (bM - M);
        int sin_ = (dq < 0) ? dq  : 0;
        int sown = (dq > 0) ? -dq : 0;
        int mup  = (dq > 0) ? dq  : 0;

        float a0 = ldexp_nat(q0, sown), a1 = ldexp_nat(q1, sown);
        float a2 = ldexp_nat(q2, sown), a3 = ldexp_nat(q3, sown);
        float b0 = ldexp_nat(bq0, sin_), b1 = ldexp_nat(bq1, sin_);
        float b2 = ldexp_nat(bq2, sin_), b3 = ldexp_nat(bq3, sin_);

        float y0 = fmaf(C1[0], b3, fmaf(C2[0], b2, fmaf(C3[0], b1, fmaf(C4[0], b0, C0[0] * a0))));
        float y1 = fmaf(C2[1], b3, fmaf(C3[1], b2, fmaf(C4[1], b1, fmaf(C1[1], a0, C0[1] * a1))));
        float y2 = fmaf(C3[2], b3, fmaf(C4[2], b2, fmaf(C1[2], a1, fmaf(C2[2], a0, C0[2] * a2))));
        float y3 = fmaf(C4[3], b3, fmaf(C1[3], a2, fmaf(C2[3], a1, fmaf(C3[3], a0, C0[3] * a3))));

        float mloc = fmaxf(fmaxf(y0, y1), fmaxf(y2, y3));
        int ex  = (int)(__float_as_uint(mloc) >> 23) - 126;
        int nex = -ex;
        q0 = ldexp_nat(y0, nex); q1 = ldexp_nat(y1, nex);
        q2 = ldexp_nat(y2, nex); q3 = ldexp_nat(y3, nex);
        int Mn = M + mup + ex;
        M = (mloc > 0.f) ? Mn : M_DEAD;
    }

    asm volatile("s_waitcnt vmcnt(0)" ::: "memory");
    __builtin_amdgcn_sched_barrier(0);

    // tail: 0..3 raw single steps on bf16 p rows (rows <= tmax <= 2047)
    {
        const int t0 = 4 * nss + 1;
        f32x4 pr0 = bf4(*(const uint2*)(sbase + (size_t)(t0 + 0) * TXT + l * 4));
        f32x4 pr1 = bf4(*(const uint2*)(sbase + (size_t)(t0 + 1) * TXT + l * 4));
        f32x4 pr2 = bf4(*(const uint2*)(sbase + (size_t)(t0 + 2) * TXT + l * 4));

#define STEP1(P)                                                   \
    {                                                              \
        float qb = wave_ror1_f(q3);                                \
        int   Mb = wave_ror1_i(M);                                 \
        int dq   = z ? (-(1 << 28)) : (Mb - M);                    \
        int si   = (dq < 0) ? dq  : 0;                             \
        int so   = (dq > 0) ? -dq : 0;                             \
        int mu   = (dq > 0) ? dq  : 0;                             \
        float a0 = ldexp_nat(q0, so), a1 = ldexp_nat(q1, so);      \
        float a2 = ldexp_nat(q2, so), a3 = ldexp_nat(q3, so);      \
        float bb = ldexp_nat(qb, si);                              \
        q0 = (a0 + bb) * (P)[0];                                   \
        q1 = (a1 + a0) * (P)[1];                                   \
        q2 = (a2 + a1) * (P)[2];                                   \
        q3 = (a3 + a2) * (P)[3];                                   \
        M += mu;                                                   \
    }
        if (tail >= 1) STEP1(pr0);
        if (tail >= 2) STEP1(pr1);
        if (tail >= 3) STEP1(pr2);
#undef STEP1
    }
#undef ISSUE_SS

    const int lf = jt >> 2;
    const int ef = jt & 3;
    float v = (ef == 0) ? q0 : (ef == 1) ? q1 : (ef == 2) ? q2 : q3;
    if (l == lf) alpha[b] = (log2_nat(v) + (float)M) * out_scale;
}

// ---------------------------------------------------------------------------
// DP fallback (un-transposed, ln-domain reads from out1) — safety net.
// ---------------------------------------------------------------------------
__global__ __launch_bounds__(256) void dp_kernel_fallback(
    const float* __restrict__ lp,
    const int* __restrict__ tlen, const int* __restrict__ mlen,
    float* __restrict__ alpha)
{
    const int b    = blockIdx.x;
    const int j    = threadIdx.x;
    const int lane = j & 63;
    const int w    = j >> 6;

    const int tl   = tlen[b];
    const int ml   = mlen[b];
    const int tmax = ml - 1;
    const int jt   = tl - 1;
    const float inv_ml = 1.0f / (float)ml;

    __shared__ float bnd[2][4];
    if (threadIdx.x < 8) bnd[threadIdx.x >> 2][threadIdx.x & 3] = NEGV;
    __syncthreads();

    float cur = (j == 0) ? lp[(size_t)(b * TXT) * MEL] : NEGV;
    if (tmax == 0) {
        if (j == jt) alpha[b] = cur * inv_ml;
        return;
    }
    int p = 0;
    for (int t = 1; t <= tmax; ++t) {
        float lpc = lp[((size_t)(b * TXT + j)) * MEL + t];
        float sh = __shfl_up(cur, 1);
        if (lane == 0) sh = (w > 0) ? bnd[p][w - 1] : NEGV;
        float mx = fmaxf(cur, sh);
        float dd = fminf(cur, sh) - mx;
        float nv = mx + __logf(1.0f + __expf(dd)) + lpc;
        if (lane == 63) bnd[p ^ 1][w] = nv;
        if (t == tmax && j == jt) alpha[b] = nv * inv_ml;
        cur = nv;
        __syncthreads();
        p ^= 1;
    }
}

// ---------------------------------------------------------------------------
// Reduce: loss = -mean_b(alpha[b])
// ---------------------------------------------------------------------------
__global__ void reduce_kernel(const float* __restrict__ alpha, float* __restrict__ out)
{
    const int tid = threadIdx.x;
    float v = (tid < B_) ? alpha[tid] : 0.f;
#pragma unroll
    for (int m = 16; m >= 1; m >>= 1) v += __shfl_xor(v, m);
    if (tid == 0) out[0] = -v / (float)B_;
}

// ---------------------------------------------------------------------------
extern "C" void kernel_launch(void* const* d_in, const int* in_sizes, int n_in,
                              void* d_out, int out_size, void* d_ws, size_t ws_size,
                              hipStream_t stream)
{
    const float* mu_logvar = (const float*)d_in[0];
    const float* melspec   = (const float*)d_in[1];
    const int*   tlen      = (const int*)d_in[2];
    const int*   mlen      = (const int*)d_in[3];
    float* out = (float*)d_out;
    float* ws  = (float*)d_ws;

    // ws layout (in float units)
    const size_t IV_OFF    = 0;                        // 655360
    const size_t M2_OFF    = 655360;                   // 655360
    const size_t S_OFF     = 1310720;                  // 8192
    const size_t ALPHA_OFF = 1318912;                  // 32
    const size_t LPT_OFF   = 1318944;                  // bf16: B*MEL*TXT u16
    const size_t LPT_FLOATS = (size_t)B_ * MEL * TXT / 2;      // 8,388,608
    const size_t LPT_PAD_F  = 2048;                    // 16 rows x 256 u16
    const size_t COEF_OFF  = LPT_OFF + LPT_FLOATS + LPT_PAD_F; // 9,709,600
    const size_t COEF_FLOATS = (size_t)B_ * GSTRIDE * 5 * 256 / 2; // 10,649,600

    float* IV    = ws + IV_OFF;
    float* M2    = ws + M2_OFF;
    float* S     = ws + S_OFF;
    float* alpha = ws + ALPHA_OFF;
    u16*   lpT   = (u16*)(ws + LPT_OFF);
    u16*   coef  = (u16*)(ws + COEF_OFF);

    const bool use_coef = ws_size >= (COEF_OFF + COEF_FLOATS) * sizeof(float);

    precompute_kernel<<<dim3(B_), dim3(256), 0, stream>>>(mu_logvar, IV, M2, S);

    logprob_kernel<<<dim3(MEL / 128, TXT / 64, B_), dim3(256), 0, stream>>>(
        melspec, IV, M2, S, out + 1, lpT, use_coef ? 1 : 0);

    if (use_coef) {
        coeff_kernel<<<dim3(64, B_), dim3(256), 0, stream>>>(lpT, coef);
        dp_super_kernel<<<dim3(B_), dim3(64), 0, stream>>>(lpT, coef, tlen, mlen, alpha);
    } else {
        dp_kernel_fallback<<<dim3(B_), dim3(256), 0, stream>>>(out + 1, tlen, mlen, alpha);
    }

    reduce_kernel<<<dim3(1), dim3(64), 0, stream>>>(alpha, out);
}